// Round 5
// baseline (435.671 us; speedup 1.0000x reference)
//
#include <hip/hip_runtime.h>

typedef __bf16 bf16_t;
typedef __attribute__((ext_vector_type(8))) __bf16 bf16x8;
typedef __attribute__((ext_vector_type(16))) float f32x16;
typedef __attribute__((ext_vector_type(8))) int i32x8;
typedef long long i64;
typedef __attribute__((ext_vector_type(2))) long long i64x2;
typedef unsigned long long u64;

#define MFMA32(A, B, C) __builtin_amdgcn_mfma_f32_32x32x16_bf16((A), (B), (C), 0, 0, 0)

// Problem constants: B=8, C=128, H=W=64 -> N=4096, R=16

// pack 4 f32 -> 4 fp8(e4m3) bytes (used in k_qkv V conversion)
__device__ __forceinline__ unsigned pk4(float a, float b, float c, float d) {
  unsigned u = __builtin_amdgcn_cvt_pk_fp8_f32(a, b, 0u, false);
  return __builtin_amdgcn_cvt_pk_fp8_f32(c, d, u, true);
}
// exchange hi-half of a with lo-half of b (v_permlane32_swap)
__device__ __forceinline__ void swap32(unsigned &a, unsigned &b) {
  asm volatile("v_permlane32_swap_b32 %0, %1" : "+v"(a), "+v"(b));
}
// value of x in partner lane (lane ^ 32)
__device__ __forceinline__ float xhalf(float x, int hi) {
  unsigned a = __builtin_bit_cast(unsigned, x), b = a;
  asm volatile("v_permlane32_swap_b32 %0, %1" : "+v"(a), "+v"(b));
  return __builtin_bit_cast(float, hi ? a : b);
}
__device__ __forceinline__ unsigned pkbf2(float a, float b) {
  union { bf16_t h[2]; unsigned u; } r;
  r.h[0] = (bf16_t)a; r.h[1] = (bf16_t)b;
  return r.u;
}

// v_cvt_pk_u8_f32: D = insert(u8(trunc(S0)) << 8*slot) into S2. One op converts,
// clamps [0,255] and packs a byte. Chained to build 4 fp8 bytes per dword.
#define CVT8_0(d, f) asm("v_cvt_pk_u8_f32 %0, %1, 0, 0" : "=v"(d) : "v"(f))
#define CVT8_N(d, f, slot) asm("v_cvt_pk_u8_f32 %0, %1, " slot ", %0" : "+v"(d) : "v"(f))

// -------- kernel 1: fused transpose + q,kT,V-fp8 projections (64-n tiles) --------
// also casts Wo f32 -> bf16 (Wob) for the fused output GEMM.
// q[b][n][r]=QS*(Wq x+bq) (log2-domain); kT[b][m][r]=Wk x+bk;
// vf fp8, K=64-MFMA A-operand tiled (R5): per (mq, sp=step-pair, ct=c-block):
//   2048B chunk at b*524288 + mq*131072 + sp*8192 + ct*2048; lane r=hi*32+c31
//   holds 32B = V[c=ct*32+c31][m = mq*1024 + sp*64 + hi*32 + 0..31]
__global__ __launch_bounds__(256) void k_qkv(
    const float* __restrict__ x,
    const float* __restrict__ Wq, const float* __restrict__ bq,
    const float* __restrict__ Wk, const float* __restrict__ bk,
    const float* __restrict__ Wv, const float* __restrict__ bv,
    const float* __restrict__ Wo,
    bf16_t* __restrict__ q, bf16_t* __restrict__ kT, char* __restrict__ vfout,
    bf16_t* __restrict__ Wob) {
  __shared__ __align__(16) bf16_t xt[64 * 136];      // [n_loc][c] bf16, stride 272B
  __shared__ __align__(16) bf16_t Wqk_s[32 * 136];
  __shared__ __align__(16) bf16_t Wv_s[128 * 152];   // stride 304B
  __shared__ __align__(8)  char   vst[128 * 72];     // fp8 stage [c][m_loc(64)+8pad]
  const float QS = 0.25f * 1.44269504f;  // scale * log2(e)
  const int b = blockIdx.y;
  const int nb = blockIdx.x;             // 64-col tile
  const int n0 = nb * 64;
  const int t = threadIdx.x;
  if (b == 0) {                          // Wo cast: 64 blocks x 256 = 16384 elems
    int i = nb * 256 + t;
    Wob[i] = (bf16_t)Wo[i];
  }
  for (int i = t; i < 32 * 128; i += 256) {
    int row = i >> 7, col = i & 127;
    float val = (row < 16) ? QS * Wq[row * 128 + col] : Wk[(row - 16) * 128 + col];
    Wqk_s[row * 136 + col] = (bf16_t)val;
  }
  for (int i = t; i < 128 * 128; i += 256)
    Wv_s[(i >> 7) * 152 + (i & 127)] = (bf16_t)Wv[i];

  // ---- one-pass transpose stage: x[c][n] f32 -> xt[n][c] bf16 ----
  const int nl = t & 63, cg = t >> 6;    // thread: n=nl, c-quarter cg
  const float* xb = x + (size_t)b * 524288 + n0 + nl;
  float xv[32];
#pragma unroll
  for (int i = 0; i < 32; ++i) xv[i] = xb[(size_t)(cg * 32 + i) * 4096];
  char* xrow = (char*)xt + nl * 272 + cg * 64;
#pragma unroll
  for (int i = 0; i < 16; ++i)
    *(unsigned*)(xrow + 4 * i) = pkbf2(xv[2 * i], xv[2 * i + 1]);
  __syncthreads();

  const int w = t >> 6, l = t & 63, l31 = l & 31, hi = l >> 5;
  const int nc = w & 1, role = w >> 1;   // waves: 2 n-chunks x 2 roles
  const int nloc = nc * 32 + l31;

  f32x16 aqk;
  f32x16 av[2];
#pragma unroll
  for (int i = 0; i < 16; ++i) { aqk[i] = 0.f; av[0][i] = 0.f; av[1][i] = 0.f; }
#pragma unroll
  for (int kk = 0; kk < 8; ++kk) {
    bf16x8 xf = *(const bf16x8*)((char*)xt + nloc * 272 + kk * 32 + hi * 16);
    if (role == 0) {
      bf16x8 wqk = *(const bf16x8*)(&Wqk_s[l31 * 136 + kk * 16 + 8 * hi]);
      aqk = MFMA32(xf, wqk, aqk);   // D[n][col]: col<16 -> q, col>=16 -> k
    }
#pragma unroll
    for (int j = 0; j < 2; ++j) {
      int ct = role * 2 + j;
      bf16x8 wvv = *(const bf16x8*)(&Wv_s[(ct * 32 + l31) * 152 + kk * 16 + 8 * hi]);
      av[j] = MFMA32(wvv, xf, av[j]);  // D[c_out][n]
    }
  }
  if (role == 0) {
    const float bias_qk = (l31 < 16) ? QS * bq[l31] : bk[l31 - 16];
#pragma unroll
    for (int r = 0; r < 16; ++r) {
      int n = n0 + nc * 32 + (r & 3) + 8 * (r >> 2) + 4 * hi;
      bf16_t vb16 = (bf16_t)(aqk[r] + bias_qk);
      if (l31 < 16) q[((size_t)(b * 4096 + n)) * 16 + l31] = vb16;
      else          kT[((size_t)(b * 4096 + n)) * 16 + (l31 - 16)] = vb16;
    }
  }

  // ---- v epilogue: fp8 convert -> vst[c][m_loc] ----
  const int mloc = nc * 32 + l31;
#pragma unroll
  for (int j = 0; j < 2; ++j) {
    int ct = role * 2 + j;
#pragma unroll
    for (int r = 0; r < 16; r += 2) {
      int c = ct * 32 + (r & 3) + 8 * (r >> 2) + 4 * hi;
      unsigned pw = pk4(av[j][r] + bv[c], av[j][r + 1] + bv[c + 1], 0.f, 0.f);
      vst[c * 72 + mloc] = (char)(pw & 0xff);
      vst[(c + 1) * 72 + mloc] = (char)((pw >> 8) & 0xff);
    }
  }
  __syncthreads();
  // ---- R5 writeout: K=64 A-operand tiling. Block covers exactly one sp (64 m).
  // thread t: ct = t>>6, r = t&63 (= MFMA lane), hi = r>>5 (pair-half), c31 = r&31.
  // Reads vst[c][hi*32 .. +32) (contiguous in mloc), writes 32B at t*32: coalesced.
  {
    char* vfb = vfout + (size_t)b * 524288 + (size_t)(nb >> 4) * 131072 + (size_t)(nb & 15) * 8192;
    const int ct = t >> 6, r = t & 63, rhi = r >> 5, c31 = r & 31;
    const char* src = vst + (ct * 32 + c31) * 72 + rhi * 32;
    u64 d0 = *(const u64*)(src);
    u64 d1 = *(const u64*)(src + 8);
    u64 d2 = *(const u64*)(src + 16);
    u64 d3 = *(const u64*)(src + 24);
    u64* dst = (u64*)(vfb + (size_t)t * 32);
    dst[0] = d0; dst[1] = d1; dst[2] = d2; dst[3] = d3;
  }
}

// -------- kernel 2: flash attention + fused Wo epilogue --------
// 512 blocks = 8 batch x 64 q-blocks(64q). 8 waves = 2 q-chunks x 4 m-quarters.
// R5 (R14): PV matrix work cut 40% via mfma_scale_f32_32x32x64_f8f6f4 (2x fp8
// rate, K=64 = TWO 32-m steps contracted per instruction, identity E8M0 scales).
// Evidence: dur invariant (~47us = 3530cy/step/SIMD) under arbitration (R1),
// V-latency hiding (R2), +-20% VALU (R3); MfmaUtil pinned 31%. Only untouched
// resource: the MFMA stream (8 K=16 fp8 PV MFMAs = 256 of 288 matrix cyc/step).
// Per step-PAIR now: 2 QK bf16 + 4 scaled = ~350 matrix-cyc vs 576, 6 MFMAs vs 18.
// B-operand falls out of existing pk4 words with the same 4 permlane-swaps,
// paired across steps: B = [w0s,w0t,w1s,w1t,w2s,w2t,w3s,w3t] after swap32(wis,wit).
// V-LDS ring dropped (R2 showed null); V loads straight from L2 (32B/lane/ct).
// R4's occupancy split reverted (64-reg cap -> spill catastrophe).
__global__ __launch_bounds__(512, 4) void k_attn(
    const bf16_t* __restrict__ q, const bf16_t* __restrict__ kT,
    const char* __restrict__ vf, const bf16_t* __restrict__ Wob,
    const float* __restrict__ bo, const float* __restrict__ gammap,
    const float* __restrict__ x, float* __restrict__ out) {
  __shared__ __align__(16) bf16_t accb[8][32][136];  // 69.6 KB
  __shared__ float lsum[8][32];
  __shared__ float linv[64];
  const int bid = blockIdx.x;
  const int b = bid & 7, qb = bid >> 3;   // batch-in-low-bits -> XCD/L2 affinity
  const int t = threadIdx.x, w = t >> 6, l = t & 63, l31 = l & 31, hi = l >> 5;
  const int qg = w & 1, mq = w >> 1;
  const int n0 = qb * 64 + qg * 32;

  const bf16_t* kw = kT + (size_t)b * 65536 + (size_t)mq * 16384;
  const char* vw = vf + (size_t)b * 524288 + (size_t)mq * 131072 + (size_t)l * 32;

  bf16x8 qf = *(const bf16x8*)(q + ((size_t)(b * 4096) + n0 + l31) * 16 + 8 * hi);
  bf16x8 kf0 = *(const bf16x8*)(kw + (size_t)l31 * 16 + 8 * hi);
  bf16x8 kf1 = *(const bf16x8*)(kw + (size_t)(32 + l31) * 16 + 8 * hi);

  f32x16 z;
#pragma unroll
  for (int i = 0; i < 16; ++i) z[i] = 0.f;
  f32x16 acc[4];
#pragma unroll
  for (int ct = 0; ct < 4; ++ct) acc[ct] = z;
  float lac = 0.f;

#pragma unroll 2
  for (int sp = 0; sp < 16; ++sp) {      // 16 step-pairs (64 m each)
    const char* vt = vw + (size_t)sp * 8192;
    i64x2 va[4][2];
#pragma unroll
    for (int ct = 0; ct < 4; ++ct) {
      va[ct][0] = *(const i64x2*)(vt + ct * 2048);
      va[ct][1] = *(const i64x2*)(vt + ct * 2048 + 16);
    }

    f32x16 st0 = MFMA32(kf0, qf, z);   // D[m][n]: m=(r&3)+8(r>>2)+4hi (rows sp*64+0..31)
    f32x16 st1 = MFMA32(kf1, qf, z);   // rows sp*64+32..63
    if (sp < 15) {
      kf0 = *(const bf16x8*)(kw + ((size_t)((sp + 1) * 64 + l31)) * 16 + 8 * hi);
      kf1 = *(const bf16x8*)(kw + ((size_t)((sp + 1) * 64 + 32 + l31)) * 16 + 8 * hi);
    }

    // ---- fast exp2 -> e4m3fn bytes: byte = trunc(8*st + 56.156) ----
    unsigned w0s, w1s, w2s, w3s, w0t, w1t, w2t, w3t;
    {
      float zb[16];
#pragma unroll
      for (int i = 0; i < 16; ++i) zb[i] = __builtin_fmaf(st0[i], 8.f, 56.156f);
      CVT8_0(w0s, zb[0]);  CVT8_N(w0s, zb[1], "1");  CVT8_N(w0s, zb[2], "2");  CVT8_N(w0s, zb[3], "3");
      CVT8_0(w1s, zb[4]);  CVT8_N(w1s, zb[5], "1");  CVT8_N(w1s, zb[6], "2");  CVT8_N(w1s, zb[7], "3");
      CVT8_0(w2s, zb[8]);  CVT8_N(w2s, zb[9], "1");  CVT8_N(w2s, zb[10], "2"); CVT8_N(w2s, zb[11], "3");
      CVT8_0(w3s, zb[12]); CVT8_N(w3s, zb[13], "1"); CVT8_N(w3s, zb[14], "2"); CVT8_N(w3s, zb[15], "3");
    }
    {
      float zb[16];
#pragma unroll
      for (int i = 0; i < 16; ++i) zb[i] = __builtin_fmaf(st1[i], 8.f, 56.156f);
      CVT8_0(w0t, zb[0]);  CVT8_N(w0t, zb[1], "1");  CVT8_N(w0t, zb[2], "2");  CVT8_N(w0t, zb[3], "3");
      CVT8_0(w1t, zb[4]);  CVT8_N(w1t, zb[5], "1");  CVT8_N(w1t, zb[6], "2");  CVT8_N(w1t, zb[7], "3");
      CVT8_0(w2t, zb[8]);  CVT8_N(w2t, zb[9], "1");  CVT8_N(w2t, zb[10], "2"); CVT8_N(w2t, zb[11], "3");
      CVT8_0(w3t, zb[12]); CVT8_N(w3t, zb[13], "1"); CVT8_N(w3t, zb[14], "2"); CVT8_N(w3t, zb[15], "3");
    }

    // ---- denominator (same linear exp2 curve) ----
    {
      float ph[16];
#pragma unroll
      for (int i = 0; i < 16; ++i) {
        float y = __builtin_fmaf(st0[i], 8388608.f, 1.06499251e9f);  // 2^23*(st+126.957)
        ph[i] = __builtin_bit_cast(float, (int)y);
      }
#pragma unroll
      for (int i = 0; i < 16; ++i) {
        float y = __builtin_fmaf(st1[i], 8388608.f, 1.06499251e9f);
        ph[i] += __builtin_bit_cast(float, (int)y);
      }
      float s0 = (ph[0] + ph[1]) + (ph[2] + ph[3]), s1 = (ph[4] + ph[5]) + (ph[6] + ph[7]);
      float s2 = (ph[8] + ph[9]) + (ph[10] + ph[11]), s3 = (ph[12] + ph[13]) + (ph[14] + ph[15]);
      lac += (s0 + s1) + (s2 + s3);
    }

    // pair-swaps: reg 2i = {hi0: step-s m-set_i, hi1: step-t m-set_i},
    //             reg 2i+1 = {hi0: step-s m-set_i+4, hi1: step-t m-set_i+4}
    swap32(w0s, w0t);
    swap32(w1s, w1t);
    swap32(w2s, w2t);
    swap32(w3s, w3t);
    i32x8 Bop;
    Bop[0] = (int)w0s; Bop[1] = (int)w0t;
    Bop[2] = (int)w1s; Bop[3] = (int)w1t;
    Bop[4] = (int)w2s; Bop[5] = (int)w2t;
    Bop[6] = (int)w3s; Bop[7] = (int)w3t;

#pragma unroll
    for (int ct = 0; ct < 4; ++ct) {
      union { i64x2 p[2]; i32x8 v; } ua;
      ua.p[0] = va[ct][0]; ua.p[1] = va[ct][1];
      acc[ct] = __builtin_amdgcn_mfma_scale_f32_32x32x64_f8f6f4(
          ua.v, Bop, acc[ct], 0, 0, 0, 0x7f7f7f7f, 0, 0x7f7f7f7f);
    }
  }

  // ---- cross-mq combine (sum of partials) ----
  float lT = lac + xhalf(lac, hi);
  if (hi == 0) lsum[w][l31] = lT;
#pragma unroll
  for (int ct = 0; ct < 4; ++ct) {
#pragma unroll
    for (int g = 0; g < 4; ++g) {
      union { unsigned short h[4]; u64 u; } pw;
#pragma unroll
      for (int j = 0; j < 4; ++j) {
        bf16_t bb = (bf16_t)acc[ct][g * 4 + j];
        pw.h[j] = __builtin_bit_cast(unsigned short, bb);
      }
      *(u64*)&accb[w][l31][ct * 32 + 8 * g + 4 * hi] = pw.u;
    }
  }
  __syncthreads();

  {
    const int rn64 = t >> 3;            // 0..63 : local n
    const int qg2 = rn64 >> 5, rn = rn64 & 31;
    const int c0 = (t & 7) * 16;
    float L = (lsum[qg2][rn] + lsum[qg2 + 2][rn]) + (lsum[qg2 + 4][rn] + lsum[qg2 + 6][rn]);
    if ((t & 7) == 0) linv[rn64] = 1.0f / L;
    float o[16];
#pragma unroll
    for (int i = 0; i < 16; ++i) o[i] = 0.f;
#pragma unroll
    for (int m2 = 0; m2 < 4; ++m2) {
#pragma unroll
      for (int h2 = 0; h2 < 2; ++h2) {
        bf16x8 ch = *(const bf16x8*)&accb[qg2 + 2 * m2][rn][c0 + h2 * 8];
#pragma unroll
        for (int e = 0; e < 8; ++e) o[h2 * 8 + e] += (float)ch[e];
      }
    }
    // write combined RAW (unnormalized) back into accb[qg2][rn][c0..c0+15]
#pragma unroll
    for (int h2 = 0; h2 < 2; ++h2) {
      bf16x8 sv;
#pragma unroll
      for (int e = 0; e < 8; ++e) sv[e] = (bf16_t)o[h2 * 8 + e];
      *(bf16x8*)&accb[qg2][rn][c0 + h2 * 8] = sv;
    }
  }
  __syncthreads();

  // ---- fused output projection: out = gamma*(Wo @ attn + bo) + x ----
  // out is stream-once -> NT store (no L2 allocate); x load stays cached.
  {
    const int obk = w >> 1, nh = w & 1;
    const int o0 = obk * 32;
    f32x16 oc;
#pragma unroll
    for (int i = 0; i < 16; ++i) oc[i] = 0.f;
#pragma unroll
    for (int kk = 0; kk < 8; ++kk) {
      bf16x8 wof = *(const bf16x8*)(Wob + (size_t)(o0 + l31) * 128 + kk * 16 + 8 * hi);
      bf16x8 cf = *(const bf16x8*)&accb[nh][l31][kk * 16 + 8 * hi];
      oc = MFMA32(wof, cf, oc);  // D[o][n], n = l31
    }
    const float g = gammap[0];
    const float iv = linv[nh * 32 + l31];
    const int ng = qb * 64 + nh * 32 + l31;
#pragma unroll
    for (int r = 0; r < 16; ++r) {
      int o_ = o0 + (r & 3) + 8 * (r >> 2) + 4 * hi;
      size_t off = ((size_t)(b * 128 + o_)) * 4096 + ng;
      __builtin_nontemporal_store(g * (oc[r] * iv + bo[o_]) + x[off], &out[off]);
    }
  }
}

extern "C" void kernel_launch(void* const* d_in, const int* in_sizes, int n_in,
                              void* d_out, int out_size, void* d_ws, size_t ws_size,
                              hipStream_t stream) {
  const float* x  = (const float*)d_in[0];
  const float* Wq = (const float*)d_in[1];
  const float* bq = (const float*)d_in[2];
  const float* Wk = (const float*)d_in[3];
  const float* bk = (const float*)d_in[4];
  const float* Wv = (const float*)d_in[5];
  const float* bv = (const float*)d_in[6];
  const float* Wo = (const float*)d_in[7];
  const float* bo = (const float*)d_in[8];
  const float* gm = (const float*)d_in[9];
  float* out = (float*)d_out;

  char* ws = (char*)d_ws;
  bf16_t* q   = (bf16_t*)(ws);                        // 1 MB [B][N][16]
  bf16_t* kT  = (bf16_t*)(ws + (size_t)(1 << 20));    // 1 MB [B][N][16]
  char*   vf  = (char*)  (ws + (size_t)(2 << 20));    // 4 MB fp8 K=64-tiled V
  bf16_t* Wob = (bf16_t*)(ws + (size_t)(6 << 20));    // 32 KB Wo bf16

  k_qkv<<<dim3(64, 8), 256, 0, stream>>>(x, Wq, bq, Wk, bk, Wv, bv, Wo, q, kT, vf, Wob);
  k_attn<<<512, 512, 0, stream>>>(q, kT, vf, Wob, bo, gm, x, out);
}

// Round 6
// 69.553 us; speedup vs baseline: 6.2639x; 6.2639x over previous
//
#include <hip/hip_runtime.h>

typedef __bf16 bf16_t;
typedef __attribute__((ext_vector_type(8))) __bf16 bf16x8;
typedef __attribute__((ext_vector_type(16))) float f32x16;
typedef __attribute__((ext_vector_type(8))) int i32x8;
typedef long long i64;
typedef __attribute__((ext_vector_type(2))) long long i64x2;
typedef unsigned long long u64;

#define MFMA32(A, B, C) __builtin_amdgcn_mfma_f32_32x32x16_bf16((A), (B), (C), 0, 0, 0)

// Problem constants: B=8, C=128, H=W=64 -> N=4096, R=16

// pack 4 f32 -> 4 fp8(e4m3) bytes (used in k_qkv V conversion)
__device__ __forceinline__ unsigned pk4(float a, float b, float c, float d) {
  unsigned u = __builtin_amdgcn_cvt_pk_fp8_f32(a, b, 0u, false);
  return __builtin_amdgcn_cvt_pk_fp8_f32(c, d, u, true);
}
// exchange hi-half of a with lo-half of b (v_permlane32_swap)
__device__ __forceinline__ void swap32(unsigned &a, unsigned &b) {
  asm volatile("v_permlane32_swap_b32 %0, %1" : "+v"(a), "+v"(b));
}
// value of x in partner lane (lane ^ 32)
__device__ __forceinline__ float xhalf(float x, int hi) {
  unsigned a = __builtin_bit_cast(unsigned, x), b = a;
  asm volatile("v_permlane32_swap_b32 %0, %1" : "+v"(a), "+v"(b));
  return __builtin_bit_cast(float, hi ? a : b);
}
__device__ __forceinline__ unsigned pkbf2(float a, float b) {
  union { bf16_t h[2]; unsigned u; } r;
  r.h[0] = (bf16_t)a; r.h[1] = (bf16_t)b;
  return r.u;
}
// async global->LDS, 16B per lane (lds dest is wave-uniform base + lane*16)
__device__ __forceinline__ void gl_lds16(const void* g, void* l) {
  __builtin_amdgcn_global_load_lds(
      (const __attribute__((address_space(1))) void*)g,
      (__attribute__((address_space(3))) void*)l, 16, 0, 0);
}

// v_cvt_pk_u8_f32: D = insert(u8(trunc(S0)) << 8*slot) into S2. One op converts,
// clamps [0,255] and packs a byte. Chained to build 4 fp8 bytes per dword.
#define CVT8_0(d, f) asm("v_cvt_pk_u8_f32 %0, %1, 0, 0" : "=v"(d) : "v"(f))
#define CVT8_N(d, f, slot) asm("v_cvt_pk_u8_f32 %0, %1, " slot ", %0" : "+v"(d) : "v"(f))

// -------- kernel 1: fused transpose + q,kT,V-fp8 projections (64-n tiles) --------
// also casts Wo f32 -> bf16 (Wob) for the fused output GEMM.
// q[b][n][r]=QS*(Wq x+bq) (log2-domain); kT[b][m][r]=Wk x+bk;
// vf fp8, K=64-MFMA A-operand tiled (verified correct in R5): per (mq, sp, ct):
//   2048B chunk at b*524288 + mq*131072 + sp*8192 + ct*2048; lane r=rhi*32+c31
//   holds 32B = V[c=ct*32+c31][m = mq*1024 + sp*64 + rhi*32 + 0..31]
__global__ __launch_bounds__(256) void k_qkv(
    const float* __restrict__ x,
    const float* __restrict__ Wq, const float* __restrict__ bq,
    const float* __restrict__ Wk, const float* __restrict__ bk,
    const float* __restrict__ Wv, const float* __restrict__ bv,
    const float* __restrict__ Wo,
    bf16_t* __restrict__ q, bf16_t* __restrict__ kT, char* __restrict__ vfout,
    bf16_t* __restrict__ Wob) {
  __shared__ __align__(16) bf16_t xt[64 * 136];      // [n_loc][c] bf16, stride 272B
  __shared__ __align__(16) bf16_t Wqk_s[32 * 136];
  __shared__ __align__(16) bf16_t Wv_s[128 * 152];   // stride 304B
  __shared__ __align__(8)  char   vst[128 * 72];     // fp8 stage [c][m_loc(64)+8pad]
  const float QS = 0.25f * 1.44269504f;  // scale * log2(e)
  const int b = blockIdx.y;
  const int nb = blockIdx.x;             // 64-col tile
  const int n0 = nb * 64;
  const int t = threadIdx.x;
  if (b == 0) {                          // Wo cast: 64 blocks x 256 = 16384 elems
    int i = nb * 256 + t;
    Wob[i] = (bf16_t)Wo[i];
  }
  for (int i = t; i < 32 * 128; i += 256) {
    int row = i >> 7, col = i & 127;
    float val = (row < 16) ? QS * Wq[row * 128 + col] : Wk[(row - 16) * 128 + col];
    Wqk_s[row * 136 + col] = (bf16_t)val;
  }
  for (int i = t; i < 128 * 128; i += 256)
    Wv_s[(i >> 7) * 152 + (i & 127)] = (bf16_t)Wv[i];

  // ---- one-pass transpose stage: x[c][n] f32 -> xt[n][c] bf16 ----
  const int nl = t & 63, cg = t >> 6;    // thread: n=nl, c-quarter cg
  const float* xb = x + (size_t)b * 524288 + n0 + nl;
  float xv[32];
#pragma unroll
  for (int i = 0; i < 32; ++i) xv[i] = xb[(size_t)(cg * 32 + i) * 4096];
  char* xrow = (char*)xt + nl * 272 + cg * 64;
#pragma unroll
  for (int i = 0; i < 16; ++i)
    *(unsigned*)(xrow + 4 * i) = pkbf2(xv[2 * i], xv[2 * i + 1]);
  __syncthreads();

  const int w = t >> 6, l = t & 63, l31 = l & 31, hi = l >> 5;
  const int nc = w & 1, role = w >> 1;   // waves: 2 n-chunks x 2 roles
  const int nloc = nc * 32 + l31;

  f32x16 aqk;
  f32x16 av[2];
#pragma unroll
  for (int i = 0; i < 16; ++i) { aqk[i] = 0.f; av[0][i] = 0.f; av[1][i] = 0.f; }
#pragma unroll
  for (int kk = 0; kk < 8; ++kk) {
    bf16x8 xf = *(const bf16x8*)((char*)xt + nloc * 272 + kk * 32 + hi * 16);
    if (role == 0) {
      bf16x8 wqk = *(const bf16x8*)(&Wqk_s[l31 * 136 + kk * 16 + 8 * hi]);
      aqk = MFMA32(xf, wqk, aqk);   // D[n][col]: col<16 -> q, col>=16 -> k
    }
#pragma unroll
    for (int j = 0; j < 2; ++j) {
      int ct = role * 2 + j;
      bf16x8 wvv = *(const bf16x8*)(&Wv_s[(ct * 32 + l31) * 152 + kk * 16 + 8 * hi]);
      av[j] = MFMA32(wvv, xf, av[j]);  // D[c_out][n]
    }
  }
  if (role == 0) {
    const float bias_qk = (l31 < 16) ? QS * bq[l31] : bk[l31 - 16];
#pragma unroll
    for (int r = 0; r < 16; ++r) {
      int n = n0 + nc * 32 + (r & 3) + 8 * (r >> 2) + 4 * hi;
      bf16_t vb16 = (bf16_t)(aqk[r] + bias_qk);
      if (l31 < 16) q[((size_t)(b * 4096 + n)) * 16 + l31] = vb16;
      else          kT[((size_t)(b * 4096 + n)) * 16 + (l31 - 16)] = vb16;
    }
  }

  // ---- v epilogue: fp8 convert -> vst[c][m_loc] ----
  const int mloc = nc * 32 + l31;
#pragma unroll
  for (int j = 0; j < 2; ++j) {
    int ct = role * 2 + j;
#pragma unroll
    for (int r = 0; r < 16; r += 2) {
      int c = ct * 32 + (r & 3) + 8 * (r >> 2) + 4 * hi;
      unsigned pw = pk4(av[j][r] + bv[c], av[j][r + 1] + bv[c + 1], 0.f, 0.f);
      vst[c * 72 + mloc] = (char)(pw & 0xff);
      vst[(c + 1) * 72 + mloc] = (char)((pw >> 8) & 0xff);
    }
  }
  __syncthreads();
  // ---- K=64 A-operand writeout (R5-verified). Block covers exactly one sp (64 m).
  // thread t: ct = t>>6, r = t&63 (= MFMA lane), rhi = r>>5 (k-half), c31 = r&31.
  {
    char* vfb = vfout + (size_t)b * 524288 + (size_t)(nb >> 4) * 131072 + (size_t)(nb & 15) * 8192;
    const int ct = t >> 6, r = t & 63, rhi = r >> 5, c31 = r & 31;
    const char* src = vst + (ct * 32 + c31) * 72 + rhi * 32;
    u64 d0 = *(const u64*)(src);
    u64 d1 = *(const u64*)(src + 8);
    u64 d2 = *(const u64*)(src + 16);
    u64 d3 = *(const u64*)(src + 24);
    u64* dst = (u64*)(vfb + (size_t)t * 32);
    dst[0] = d0; dst[1] = d1; dst[2] = d2; dst[3] = d3;
  }
}

// -------- kernel 2: flash attention + fused Wo epilogue --------
// 512 blocks = 8 batch x 64 q-blocks(64q). 8 waves = 2 q-chunks x 4 m-quarters.
// R6 = R5's K=64 scaled-MFMA PV (numerically verified) made VGPR-NEUTRAL:
//  - V staged via global_load_lds (zero data-VGPR cost) into a 2x32KB LDS
//    double-buffer aliased over the dead accb scratch; per-ct i32x8 A-operands
//    ds_read one ct ahead (peak 16 VGPR for V, vs R5's 32 which spilled).
//  - st0/st1 produced and consumed SERIALLY (kills the 32-reg score range).
// Matrix work per step-pair: 2 QK bf16 + 4 scaled = 0.56x the old 18 MFMAs.
// Spill tripwire: FETCH must stay ~12MB (R4/R5 ballooned to >600MB).
__global__ __launch_bounds__(512, 4) void k_attn(
    const bf16_t* __restrict__ q, const bf16_t* __restrict__ kT,
    const char* __restrict__ vf, const bf16_t* __restrict__ Wob,
    const float* __restrict__ bo, const float* __restrict__ gammap,
    const float* __restrict__ x, float* __restrict__ out) {
  __shared__ __align__(16) bf16_t accb[8][32][136];  // 69.6 KB (main loop: 64KB V ring alias)
  __shared__ float lsum[8][32];
  __shared__ float linv[64];
  const int bid = blockIdx.x;
  const int b = bid & 7, qb = bid >> 3;   // batch-in-low-bits -> XCD/L2 affinity
  const int t = threadIdx.x, w = t >> 6, l = t & 63, l31 = l & 31, hi = l >> 5;
  const int qg = w & 1, mq = w >> 1;
  const int n0 = qb * 64 + qg * 32;

  const bf16_t* kw = kT + (size_t)b * 65536 + (size_t)mq * 16384;

  bf16x8 qf = *(const bf16x8*)(q + ((size_t)(b * 4096) + n0 + l31) * 16 + 8 * hi);
  bf16x8 kf0 = *(const bf16x8*)(kw + (size_t)l31 * 16 + 8 * hi);
  bf16x8 kf1 = *(const bf16x8*)(kw + (size_t)(32 + l31) * 16 + 8 * hi);

  // ---- V LDS double-buffer: 2 x 32KB aliased over accb ----
  // stage role: wave w = (ms = w>>1, hf = w&1) stages 4KB: cts {2hf,2hf+1} x 2 units
  //   src: vsrc + ms*131072 + sp*8192 + hf*4096 + i*1024 + l*16   (i=0..3)
  //   dst: ring[q] + ms*8192 + hf*4096 + i*1024                    (uniform + lane*16)
  char* const vls = (char*)&accb[0][0][0];
  const char* vsrc = vf + (size_t)b * 524288;
  const int ms = w >> 1, hf = w & 1;
  const size_t gsb = (size_t)ms * 131072 + (size_t)hf * 4096 + (size_t)l * 16;
  const int dsb = ms * 8192 + hf * 4096;
  {  // prologue: stage sp=0 into buf0
    const char* s = vsrc + gsb;
    char* d = vls + dsb;
    gl_lds16(s, d); gl_lds16(s + 1024, d + 1024);
    gl_lds16(s + 2048, d + 2048); gl_lds16(s + 3072, d + 3072);
  }

  f32x16 z;
#pragma unroll
  for (int i = 0; i < 16; ++i) z[i] = 0.f;
  f32x16 acc[4];
#pragma unroll
  for (int ct = 0; ct < 4; ++ct) acc[ct] = z;
  float lac = 0.f;

#pragma unroll 1
  for (int sp = 0; sp < 16; ++sp) {      // 16 step-pairs (64 m each)
    __syncthreads();                     // ring[sp&1] staged & visible; prev reads done
    char* rb = vls + (sp & 1) * 32768;
    if (sp < 15) {                       // stage sp+1 into the other buffer
      const char* s = vsrc + gsb + (size_t)(sp + 1) * 8192;
      char* d = vls + ((sp + 1) & 1) * 32768 + dsb;
      gl_lds16(s, d); gl_lds16(s + 1024, d + 1024);
      gl_lds16(s + 2048, d + 2048); gl_lds16(s + 3072, d + 3072);
    }
    const char* vrd = rb + mq * 8192 + (size_t)l * 32;
    // issue ct0 A-operand reads early (land during pack phase)
    union { i64x2 p[2]; i32x8 v; } ua, ub;
    ua.p[0] = *(const i64x2*)(vrd);
    ua.p[1] = *(const i64x2*)(vrd + 16);

    // ---- QK + pack, serialized st0 then st1 (register pressure) ----
    unsigned w0s, w1s, w2s, w3s, w0t, w1t, w2t, w3t;
    {
      f32x16 st0 = MFMA32(kf0, qf, z);   // D[m][n]: m=(r&3)+8(r>>2)+4hi (rows sp*64+0..31)
      if (sp < 15) kf0 = *(const bf16x8*)(kw + ((size_t)((sp + 1) * 64 + l31)) * 16 + 8 * hi);
      float zb[16];
#pragma unroll
      for (int i = 0; i < 16; ++i) zb[i] = __builtin_fmaf(st0[i], 8.f, 56.156f);
      CVT8_0(w0s, zb[0]);  CVT8_N(w0s, zb[1], "1");  CVT8_N(w0s, zb[2], "2");  CVT8_N(w0s, zb[3], "3");
      CVT8_0(w1s, zb[4]);  CVT8_N(w1s, zb[5], "1");  CVT8_N(w1s, zb[6], "2");  CVT8_N(w1s, zb[7], "3");
      CVT8_0(w2s, zb[8]);  CVT8_N(w2s, zb[9], "1");  CVT8_N(w2s, zb[10], "2"); CVT8_N(w2s, zb[11], "3");
      CVT8_0(w3s, zb[12]); CVT8_N(w3s, zb[13], "1"); CVT8_N(w3s, zb[14], "2"); CVT8_N(w3s, zb[15], "3");
      float ph[16];
#pragma unroll
      for (int i = 0; i < 16; ++i) {
        float y = __builtin_fmaf(st0[i], 8388608.f, 1.06499251e9f);  // 2^23*(st+126.957)
        ph[i] = __builtin_bit_cast(float, (int)y);
      }
      float s0 = (ph[0] + ph[1]) + (ph[2] + ph[3]), s1 = (ph[4] + ph[5]) + (ph[6] + ph[7]);
      float s2 = (ph[8] + ph[9]) + (ph[10] + ph[11]), s3 = (ph[12] + ph[13]) + (ph[14] + ph[15]);
      lac += (s0 + s1) + (s2 + s3);
    }
    {
      f32x16 st1 = MFMA32(kf1, qf, z);   // rows sp*64+32..63
      if (sp < 15) kf1 = *(const bf16x8*)(kw + ((size_t)((sp + 1) * 64 + 32 + l31)) * 16 + 8 * hi);
      float zb[16];
#pragma unroll
      for (int i = 0; i < 16; ++i) zb[i] = __builtin_fmaf(st1[i], 8.f, 56.156f);
      CVT8_0(w0t, zb[0]);  CVT8_N(w0t, zb[1], "1");  CVT8_N(w0t, zb[2], "2");  CVT8_N(w0t, zb[3], "3");
      CVT8_0(w1t, zb[4]);  CVT8_N(w1t, zb[5], "1");  CVT8_N(w1t, zb[6], "2");  CVT8_N(w1t, zb[7], "3");
      CVT8_0(w2t, zb[8]);  CVT8_N(w2t, zb[9], "1");  CVT8_N(w2t, zb[10], "2"); CVT8_N(w2t, zb[11], "3");
      CVT8_0(w3t, zb[12]); CVT8_N(w3t, zb[13], "1"); CVT8_N(w3t, zb[14], "2"); CVT8_N(w3t, zb[15], "3");
      float ph[16];
#pragma unroll
      for (int i = 0; i < 16; ++i) {
        float y = __builtin_fmaf(st1[i], 8388608.f, 1.06499251e9f);
        ph[i] = __builtin_bit_cast(float, (int)y);
      }
      float s0 = (ph[0] + ph[1]) + (ph[2] + ph[3]), s1 = (ph[4] + ph[5]) + (ph[6] + ph[7]);
      float s2 = (ph[8] + ph[9]) + (ph[10] + ph[11]), s3 = (ph[12] + ph[13]) + (ph[14] + ph[15]);
      lac += (s0 + s1) + (s2 + s3);
    }

    // pair-swaps (R5-verified): reg 2i = {hi0: st0 m-set_i, hi1: st1 m-set_i}
    swap32(w0s, w0t);
    swap32(w1s, w1t);
    swap32(w2s, w2t);
    swap32(w3s, w3t);
    i32x8 Bop;
    Bop[0] = (int)w0s; Bop[1] = (int)w0t;
    Bop[2] = (int)w1s; Bop[3] = (int)w1t;
    Bop[4] = (int)w2s; Bop[5] = (int)w2t;
    Bop[6] = (int)w3s; Bop[7] = (int)w3t;

    // ---- PV: 4 scaled K=64 MFMAs, A-operand ds_read one ct ahead ----
#pragma unroll
    for (int ct = 0; ct < 4; ++ct) {
      if (ct < 3) {
        ub.p[0] = *(const i64x2*)(vrd + (ct + 1) * 2048);
        ub.p[1] = *(const i64x2*)(vrd + (ct + 1) * 2048 + 16);
      }
      acc[ct] = __builtin_amdgcn_mfma_scale_f32_32x32x64_f8f6f4(
          ua.v, Bop, acc[ct], 0, 0, 0, 0x7f7f7f7f, 0, 0x7f7f7f7f);
      ua = ub;
    }
  }
  __syncthreads();   // all waves done reading V ring before accb overwrites it

  // ---- cross-mq combine (sum of partials) ----
  float lT = lac + xhalf(lac, hi);
  if (hi == 0) lsum[w][l31] = lT;
#pragma unroll
  for (int ct = 0; ct < 4; ++ct) {
#pragma unroll
    for (int g = 0; g < 4; ++g) {
      union { unsigned short h[4]; u64 u; } pw;
#pragma unroll
      for (int j = 0; j < 4; ++j) {
        bf16_t bb = (bf16_t)acc[ct][g * 4 + j];
        pw.h[j] = __builtin_bit_cast(unsigned short, bb);
      }
      *(u64*)&accb[w][l31][ct * 32 + 8 * g + 4 * hi] = pw.u;
    }
  }
  __syncthreads();

  {
    const int rn64 = t >> 3;            // 0..63 : local n
    const int qg2 = rn64 >> 5, rn = rn64 & 31;
    const int c0 = (t & 7) * 16;
    float L = (lsum[qg2][rn] + lsum[qg2 + 2][rn]) + (lsum[qg2 + 4][rn] + lsum[qg2 + 6][rn]);
    if ((t & 7) == 0) linv[rn64] = 1.0f / L;
    float o[16];
#pragma unroll
    for (int i = 0; i < 16; ++i) o[i] = 0.f;
#pragma unroll
    for (int m2 = 0; m2 < 4; ++m2) {
#pragma unroll
      for (int h2 = 0; h2 < 2; ++h2) {
        bf16x8 ch = *(const bf16x8*)&accb[qg2 + 2 * m2][rn][c0 + h2 * 8];
#pragma unroll
        for (int e = 0; e < 8; ++e) o[h2 * 8 + e] += (float)ch[e];
      }
    }
    // write combined RAW (unnormalized) back into accb[qg2][rn][c0..c0+15]
#pragma unroll
    for (int h2 = 0; h2 < 2; ++h2) {
      bf16x8 sv;
#pragma unroll
      for (int e = 0; e < 8; ++e) sv[e] = (bf16_t)o[h2 * 8 + e];
      *(bf16x8*)&accb[qg2][rn][c0 + h2 * 8] = sv;
    }
  }
  __syncthreads();

  // ---- fused output projection: out = gamma*(Wo @ attn + bo) + x ----
  // out is stream-once -> NT store (no L2 allocate); x load stays cached.
  {
    const int obk = w >> 1, nh = w & 1;
    const int o0 = obk * 32;
    f32x16 oc;
#pragma unroll
    for (int i = 0; i < 16; ++i) oc[i] = 0.f;
#pragma unroll
    for (int kk = 0; kk < 8; ++kk) {
      bf16x8 wof = *(const bf16x8*)(Wob + (size_t)(o0 + l31) * 128 + kk * 16 + 8 * hi);
      bf16x8 cf = *(const bf16x8*)&accb[nh][l31][kk * 16 + 8 * hi];
      oc = MFMA32(wof, cf, oc);  // D[o][n], n = l31
    }
    const float g = gammap[0];
    const float iv = linv[nh * 32 + l31];
    const int ng = qb * 64 + nh * 32 + l31;
#pragma unroll
    for (int r = 0; r < 16; ++r) {
      int o_ = o0 + (r & 3) + 8 * (r >> 2) + 4 * hi;
      size_t off = ((size_t)(b * 128 + o_)) * 4096 + ng;
      __builtin_nontemporal_store(g * (oc[r] * iv + bo[o_]) + x[off], &out[off]);
    }
  }
}

extern "C" void kernel_launch(void* const* d_in, const int* in_sizes, int n_in,
                              void* d_out, int out_size, void* d_ws, size_t ws_size,
                              hipStream_t stream) {
  const float* x  = (const float*)d_in[0];
  const float* Wq = (const float*)d_in[1];
  const float* bq = (const float*)d_in[2];
  const float* Wk = (const float*)d_in[3];
  const float* bk = (const float*)d_in[4];
  const float* Wv = (const float*)d_in[5];
  const float* bv = (const float*)d_in[6];
  const float* Wo = (const float*)d_in[7];
  const float* bo = (const float*)d_in[8];
  const float* gm = (const float*)d_in[9];
  float* out = (float*)d_out;

  char* ws = (char*)d_ws;
  bf16_t* q   = (bf16_t*)(ws);                        // 1 MB [B][N][16]
  bf16_t* kT  = (bf16_t*)(ws + (size_t)(1 << 20));    // 1 MB [B][N][16]
  char*   vf  = (char*)  (ws + (size_t)(2 << 20));    // 4 MB fp8 K=64-tiled V
  bf16_t* Wob = (bf16_t*)(ws + (size_t)(6 << 20));    // 32 KB Wo bf16

  k_qkv<<<dim3(64, 8), 256, 0, stream>>>(x, Wq, bq, Wk, bk, Wv, bv, Wo, q, kT, vf, Wob);
  k_attn<<<512, 512, 0, stream>>>(q, kT, vf, Wob, bo, gm, x, out);
}

// Round 7
// 69.477 us; speedup vs baseline: 6.2707x; 1.0011x over previous
//
#include <hip/hip_runtime.h>

typedef __bf16 bf16_t;
typedef __attribute__((ext_vector_type(8))) __bf16 bf16x8;
typedef __attribute__((ext_vector_type(16))) float f32x16;
typedef __attribute__((ext_vector_type(8))) int i32x8;
typedef long long i64;
typedef __attribute__((ext_vector_type(2))) long long i64x2;
typedef unsigned long long u64;

#define MFMA32(A, B, C) __builtin_amdgcn_mfma_f32_32x32x16_bf16((A), (B), (C), 0, 0, 0)

// Problem constants: B=8, C=128, H=W=64 -> N=4096, R=16

// pack 4 f32 -> 4 fp8(e4m3) bytes (used in k_qkv V conversion)
__device__ __forceinline__ unsigned pk4(float a, float b, float c, float d) {
  unsigned u = __builtin_amdgcn_cvt_pk_fp8_f32(a, b, 0u, false);
  return __builtin_amdgcn_cvt_pk_fp8_f32(c, d, u, true);
}
// exchange hi-half of a with lo-half of b (v_permlane32_swap)
__device__ __forceinline__ void swap32(unsigned &a, unsigned &b) {
  asm volatile("v_permlane32_swap_b32 %0, %1" : "+v"(a), "+v"(b));
}
// value of x in partner lane (lane ^ 32)
__device__ __forceinline__ float xhalf(float x, int hi) {
  unsigned a = __builtin_bit_cast(unsigned, x), b = a;
  asm volatile("v_permlane32_swap_b32 %0, %1" : "+v"(a), "+v"(b));
  return __builtin_bit_cast(float, hi ? a : b);
}
__device__ __forceinline__ unsigned pkbf2(float a, float b) {
  union { bf16_t h[2]; unsigned u; } r;
  r.h[0] = (bf16_t)a; r.h[1] = (bf16_t)b;
  return r.u;
}
// async global->LDS, 16B per lane (lds dest is wave-uniform base + lane*16)
__device__ __forceinline__ void gl_lds16(const void* g, void* l) {
  __builtin_amdgcn_global_load_lds(
      (const __attribute__((address_space(1))) void*)g,
      (__attribute__((address_space(3))) void*)l, 16, 0, 0);
}

// v_cvt_pk_u8_f32: D = insert(u8(trunc(S0)) << 8*slot) into S2. One op converts,
// clamps [0,255] and packs a byte. Chained to build 4 fp8 bytes per dword.
#define CVT8_0(d, f) asm("v_cvt_pk_u8_f32 %0, %1, 0, 0" : "=v"(d) : "v"(f))
#define CVT8_N(d, f, slot) asm("v_cvt_pk_u8_f32 %0, %1, " slot ", %0" : "+v"(d) : "v"(f))

// -------- kernel 1: fused transpose + q,kT,V-fp8 projections (64-n tiles) --------
// also casts Wo f32 -> bf16 (Wob) for the fused output GEMM.
// q[b][n][r]=QS*(Wq x+bq) (log2-domain); kT[b][m][r]=Wk x+bk;
// vf fp8, K=64 A-operand tiled, R7 SPLIT-PLANE (conflict-free ds_read):
//   chunk(mq,sp,ct) = 2KB at b*524288 + mq*131072 + sp*8192 + ct*2048
//   plane0 (bytes 0-1023):    lane r's FIRST 16B of A-operand at r*16
//   plane1 (bytes 1024-2047): lane r's SECOND 16B at 1024 + r*16
//   (lane r = rhi*32+c31 holds V[c=ct*32+c31][m = mq*1024+sp*64+rhi*32 + 0..31])
__global__ __launch_bounds__(256) void k_qkv(
    const float* __restrict__ x,
    const float* __restrict__ Wq, const float* __restrict__ bq,
    const float* __restrict__ Wk, const float* __restrict__ bk,
    const float* __restrict__ Wv, const float* __restrict__ bv,
    const float* __restrict__ Wo,
    bf16_t* __restrict__ q, bf16_t* __restrict__ kT, char* __restrict__ vfout,
    bf16_t* __restrict__ Wob) {
  __shared__ __align__(16) bf16_t xt[64 * 136];      // [n_loc][c] bf16, stride 272B
  __shared__ __align__(16) bf16_t Wqk_s[32 * 136];
  __shared__ __align__(16) bf16_t Wv_s[128 * 152];   // stride 304B
  __shared__ __align__(8)  char   vst[128 * 72];     // fp8 stage [c][m_loc(64)+8pad]
  const float QS = 0.25f * 1.44269504f;  // scale * log2(e)
  const int b = blockIdx.y;
  const int nb = blockIdx.x;             // 64-col tile
  const int n0 = nb * 64;
  const int t = threadIdx.x;
  if (b == 0) {                          // Wo cast: 64 blocks x 256 = 16384 elems
    int i = nb * 256 + t;
    Wob[i] = (bf16_t)Wo[i];
  }
  for (int i = t; i < 32 * 128; i += 256) {
    int row = i >> 7, col = i & 127;
    float val = (row < 16) ? QS * Wq[row * 128 + col] : Wk[(row - 16) * 128 + col];
    Wqk_s[row * 136 + col] = (bf16_t)val;
  }
  for (int i = t; i < 128 * 128; i += 256)
    Wv_s[(i >> 7) * 152 + (i & 127)] = (bf16_t)Wv[i];

  // ---- one-pass transpose stage: x[c][n] f32 -> xt[n][c] bf16 ----
  const int nl = t & 63, cg = t >> 6;    // thread: n=nl, c-quarter cg
  const float* xb = x + (size_t)b * 524288 + n0 + nl;
  float xv[32];
#pragma unroll
  for (int i = 0; i < 32; ++i) xv[i] = xb[(size_t)(cg * 32 + i) * 4096];
  char* xrow = (char*)xt + nl * 272 + cg * 64;
#pragma unroll
  for (int i = 0; i < 16; ++i)
    *(unsigned*)(xrow + 4 * i) = pkbf2(xv[2 * i], xv[2 * i + 1]);
  __syncthreads();

  const int w = t >> 6, l = t & 63, l31 = l & 31, hi = l >> 5;
  const int nc = w & 1, role = w >> 1;   // waves: 2 n-chunks x 2 roles
  const int nloc = nc * 32 + l31;

  f32x16 aqk;
  f32x16 av[2];
#pragma unroll
  for (int i = 0; i < 16; ++i) { aqk[i] = 0.f; av[0][i] = 0.f; av[1][i] = 0.f; }
#pragma unroll
  for (int kk = 0; kk < 8; ++kk) {
    bf16x8 xf = *(const bf16x8*)((char*)xt + nloc * 272 + kk * 32 + hi * 16);
    if (role == 0) {
      bf16x8 wqk = *(const bf16x8*)(&Wqk_s[l31 * 136 + kk * 16 + 8 * hi]);
      aqk = MFMA32(xf, wqk, aqk);   // D[n][col]: col<16 -> q, col>=16 -> k
    }
#pragma unroll
    for (int j = 0; j < 2; ++j) {
      int ct = role * 2 + j;
      bf16x8 wvv = *(const bf16x8*)(&Wv_s[(ct * 32 + l31) * 152 + kk * 16 + 8 * hi]);
      av[j] = MFMA32(wvv, xf, av[j]);  // D[c_out][n]
    }
  }
  if (role == 0) {
    const float bias_qk = (l31 < 16) ? QS * bq[l31] : bk[l31 - 16];
#pragma unroll
    for (int r = 0; r < 16; ++r) {
      int n = n0 + nc * 32 + (r & 3) + 8 * (r >> 2) + 4 * hi;
      bf16_t vb16 = (bf16_t)(aqk[r] + bias_qk);
      if (l31 < 16) q[((size_t)(b * 4096 + n)) * 16 + l31] = vb16;
      else          kT[((size_t)(b * 4096 + n)) * 16 + (l31 - 16)] = vb16;
    }
  }

  // ---- v epilogue: fp8 convert -> vst[c][m_loc] ----
  const int mloc = nc * 32 + l31;
#pragma unroll
  for (int j = 0; j < 2; ++j) {
    int ct = role * 2 + j;
#pragma unroll
    for (int r = 0; r < 16; r += 2) {
      int c = ct * 32 + (r & 3) + 8 * (r >> 2) + 4 * hi;
      unsigned pw = pk4(av[j][r] + bv[c], av[j][r + 1] + bv[c + 1], 0.f, 0.f);
      vst[c * 72 + mloc] = (char)(pw & 0xff);
      vst[(c + 1) * 72 + mloc] = (char)((pw >> 8) & 0xff);
    }
  }
  __syncthreads();
  // ---- K=64 A-operand writeout, SPLIT-PLANE. Block covers exactly one sp (64 m).
  // thread t: ct = t>>6, r = t&63 (= MFMA lane), rhi = r>>5 (k-half), c31 = r&31.
  // plane0 gets lane r's first 16B at ct*2048 + r*16; plane1 the second 16B at +1024.
  {
    char* vfb = vfout + (size_t)b * 524288 + (size_t)(nb >> 4) * 131072 + (size_t)(nb & 15) * 8192;
    const int ct = t >> 6, r = t & 63, rhi = r >> 5, c31 = r & 31;
    const char* src = vst + (ct * 32 + c31) * 72 + rhi * 32;
    u64 d0 = *(const u64*)(src);
    u64 d1 = *(const u64*)(src + 8);
    u64 d2 = *(const u64*)(src + 16);
    u64 d3 = *(const u64*)(src + 24);
    u64* dst0 = (u64*)(vfb + (size_t)ct * 2048 + (size_t)r * 16);
    u64* dst1 = (u64*)(vfb + (size_t)ct * 2048 + 1024 + (size_t)r * 16);
    dst0[0] = d0; dst0[1] = d1;
    dst1[0] = d2; dst1[1] = d3;
  }
}

// -------- kernel 2: flash attention + fused Wo epilogue --------
// 512 blocks = 8 batch x 64 q-blocks(64q). 8 waves = 2 q-chunks x 4 m-quarters.
// R6: K=64 scaled-MFMA PV (verified), V via global_load_lds 2x32KB double-buffer
// aliased over accb, st0/st1 serialized (VGPR-neutral; no spill, VGPR=64).
// R7: R6 was LDS-BANK-CONFLICT-BOUND (2.56M conflict cycles; lane-stride-32B
// ds_read = 16-way conflict; 8.7K LDS-pipe cyc/sp/CU == measured 8.7K cyc/sp).
// Fix: split-plane vf layout (written by k_qkv) -> both PV A-operand reads are
// lane-contiguous stride-16 ds_read_b128 (canonical conflict-free pattern).
__global__ __launch_bounds__(512, 4) void k_attn(
    const bf16_t* __restrict__ q, const bf16_t* __restrict__ kT,
    const char* __restrict__ vf, const bf16_t* __restrict__ Wob,
    const float* __restrict__ bo, const float* __restrict__ gammap,
    const float* __restrict__ x, float* __restrict__ out) {
  __shared__ __align__(16) bf16_t accb[8][32][136];  // 69.6 KB (main loop: 64KB V ring alias)
  __shared__ float lsum[8][32];
  __shared__ float linv[64];
  const int bid = blockIdx.x;
  const int b = bid & 7, qb = bid >> 3;   // batch-in-low-bits -> XCD/L2 affinity
  const int t = threadIdx.x, w = t >> 6, l = t & 63, l31 = l & 31, hi = l >> 5;
  const int qg = w & 1, mq = w >> 1;
  const int n0 = qb * 64 + qg * 32;

  const bf16_t* kw = kT + (size_t)b * 65536 + (size_t)mq * 16384;

  bf16x8 qf = *(const bf16x8*)(q + ((size_t)(b * 4096) + n0 + l31) * 16 + 8 * hi);
  bf16x8 kf0 = *(const bf16x8*)(kw + (size_t)l31 * 16 + 8 * hi);
  bf16x8 kf1 = *(const bf16x8*)(kw + (size_t)(32 + l31) * 16 + 8 * hi);

  // ---- V LDS double-buffer: 2 x 32KB aliased over accb ----
  // stage role: wave w = (ms = w>>1, hf = w&1) stages 4KB (linear byte copy;
  // split-plane layout is transparent to staging):
  //   src: vsrc + ms*131072 + sp*8192 + hf*4096 + i*1024 + l*16   (i=0..3)
  //   dst: ring[q] + ms*8192 + hf*4096 + i*1024                    (uniform + lane*16)
  char* const vls = (char*)&accb[0][0][0];
  const char* vsrc = vf + (size_t)b * 524288;
  const int ms = w >> 1, hf = w & 1;
  const size_t gsb = (size_t)ms * 131072 + (size_t)hf * 4096 + (size_t)l * 16;
  const int dsb = ms * 8192 + hf * 4096;
  {  // prologue: stage sp=0 into buf0
    const char* s = vsrc + gsb;
    char* d = vls + dsb;
    gl_lds16(s, d); gl_lds16(s + 1024, d + 1024);
    gl_lds16(s + 2048, d + 2048); gl_lds16(s + 3072, d + 3072);
  }

  f32x16 z;
#pragma unroll
  for (int i = 0; i < 16; ++i) z[i] = 0.f;
  f32x16 acc[4];
#pragma unroll
  for (int ct = 0; ct < 4; ++ct) acc[ct] = z;
  float lac = 0.f;

#pragma unroll 1
  for (int sp = 0; sp < 16; ++sp) {      // 16 step-pairs (64 m each)
    __syncthreads();                     // ring[sp&1] staged & visible; prev reads done
    char* rb = vls + (sp & 1) * 32768;
    if (sp < 15) {                       // stage sp+1 into the other buffer
      const char* s = vsrc + gsb + (size_t)(sp + 1) * 8192;
      char* d = vls + ((sp + 1) & 1) * 32768 + dsb;
      gl_lds16(s, d); gl_lds16(s + 1024, d + 1024);
      gl_lds16(s + 2048, d + 2048); gl_lds16(s + 3072, d + 3072);
    }
    const char* vrd = rb + mq * 8192 + (size_t)l * 16;
    // issue ct0 A-operand reads early (land during pack phase); stride-16 planes
    union { i64x2 p[2]; i32x8 v; } ua, ub;
    ua.p[0] = *(const i64x2*)(vrd);
    ua.p[1] = *(const i64x2*)(vrd + 1024);

    // ---- QK + pack, serialized st0 then st1 (register pressure) ----
    unsigned w0s, w1s, w2s, w3s, w0t, w1t, w2t, w3t;
    {
      f32x16 st0 = MFMA32(kf0, qf, z);   // D[m][n]: m=(r&3)+8(r>>2)+4hi (rows sp*64+0..31)
      if (sp < 15) kf0 = *(const bf16x8*)(kw + ((size_t)((sp + 1) * 64 + l31)) * 16 + 8 * hi);
      float zb[16];
#pragma unroll
      for (int i = 0; i < 16; ++i) zb[i] = __builtin_fmaf(st0[i], 8.f, 56.156f);
      CVT8_0(w0s, zb[0]);  CVT8_N(w0s, zb[1], "1");  CVT8_N(w0s, zb[2], "2");  CVT8_N(w0s, zb[3], "3");
      CVT8_0(w1s, zb[4]);  CVT8_N(w1s, zb[5], "1");  CVT8_N(w1s, zb[6], "2");  CVT8_N(w1s, zb[7], "3");
      CVT8_0(w2s, zb[8]);  CVT8_N(w2s, zb[9], "1");  CVT8_N(w2s, zb[10], "2"); CVT8_N(w2s, zb[11], "3");
      CVT8_0(w3s, zb[12]); CVT8_N(w3s, zb[13], "1"); CVT8_N(w3s, zb[14], "2"); CVT8_N(w3s, zb[15], "3");
      float ph[16];
#pragma unroll
      for (int i = 0; i < 16; ++i) {
        float y = __builtin_fmaf(st0[i], 8388608.f, 1.06499251e9f);  // 2^23*(st+126.957)
        ph[i] = __builtin_bit_cast(float, (int)y);
      }
      float s0 = (ph[0] + ph[1]) + (ph[2] + ph[3]), s1 = (ph[4] + ph[5]) + (ph[6] + ph[7]);
      float s2 = (ph[8] + ph[9]) + (ph[10] + ph[11]), s3 = (ph[12] + ph[13]) + (ph[14] + ph[15]);
      lac += (s0 + s1) + (s2 + s3);
    }
    {
      f32x16 st1 = MFMA32(kf1, qf, z);   // rows sp*64+32..63
      if (sp < 15) kf1 = *(const bf16x8*)(kw + ((size_t)((sp + 1) * 64 + 32 + l31)) * 16 + 8 * hi);
      float zb[16];
#pragma unroll
      for (int i = 0; i < 16; ++i) zb[i] = __builtin_fmaf(st1[i], 8.f, 56.156f);
      CVT8_0(w0t, zb[0]);  CVT8_N(w0t, zb[1], "1");  CVT8_N(w0t, zb[2], "2");  CVT8_N(w0t, zb[3], "3");
      CVT8_0(w1t, zb[4]);  CVT8_N(w1t, zb[5], "1");  CVT8_N(w1t, zb[6], "2");  CVT8_N(w1t, zb[7], "3");
      CVT8_0(w2t, zb[8]);  CVT8_N(w2t, zb[9], "1");  CVT8_N(w2t, zb[10], "2"); CVT8_N(w2t, zb[11], "3");
      CVT8_0(w3t, zb[12]); CVT8_N(w3t, zb[13], "1"); CVT8_N(w3t, zb[14], "2"); CVT8_N(w3t, zb[15], "3");
      float ph[16];
#pragma unroll
      for (int i = 0; i < 16; ++i) {
        float y = __builtin_fmaf(st1[i], 8388608.f, 1.06499251e9f);
        ph[i] = __builtin_bit_cast(float, (int)y);
      }
      float s0 = (ph[0] + ph[1]) + (ph[2] + ph[3]), s1 = (ph[4] + ph[5]) + (ph[6] + ph[7]);
      float s2 = (ph[8] + ph[9]) + (ph[10] + ph[11]), s3 = (ph[12] + ph[13]) + (ph[14] + ph[15]);
      lac += (s0 + s1) + (s2 + s3);
    }

    // pair-swaps (R5-verified): reg 2i = {hi0: st0 m-set_i, hi1: st1 m-set_i}
    swap32(w0s, w0t);
    swap32(w1s, w1t);
    swap32(w2s, w2t);
    swap32(w3s, w3t);
    i32x8 Bop;
    Bop[0] = (int)w0s; Bop[1] = (int)w0t;
    Bop[2] = (int)w1s; Bop[3] = (int)w1t;
    Bop[4] = (int)w2s; Bop[5] = (int)w2t;
    Bop[6] = (int)w3s; Bop[7] = (int)w3t;

    // ---- PV: 4 scaled K=64 MFMAs, A-operand ds_read one ct ahead ----
#pragma unroll
    for (int ct = 0; ct < 4; ++ct) {
      if (ct < 3) {
        ub.p[0] = *(const i64x2*)(vrd + (ct + 1) * 2048);
        ub.p[1] = *(const i64x2*)(vrd + (ct + 1) * 2048 + 1024);
      }
      acc[ct] = __builtin_amdgcn_mfma_scale_f32_32x32x64_f8f6f4(
          ua.v, Bop, acc[ct], 0, 0, 0, 0x7f7f7f7f, 0, 0x7f7f7f7f);
      ua = ub;
    }
  }
  __syncthreads();   // all waves done reading V ring before accb overwrites it

  // ---- cross-mq combine (sum of partials) ----
  float lT = lac + xhalf(lac, hi);
  if (hi == 0) lsum[w][l31] = lT;
#pragma unroll
  for (int ct = 0; ct < 4; ++ct) {
#pragma unroll
    for (int g = 0; g < 4; ++g) {
      union { unsigned short h[4]; u64 u; } pw;
#pragma unroll
      for (int j = 0; j < 4; ++j) {
        bf16_t bb = (bf16_t)acc[ct][g * 4 + j];
        pw.h[j] = __builtin_bit_cast(unsigned short, bb);
      }
      *(u64*)&accb[w][l31][ct * 32 + 8 * g + 4 * hi] = pw.u;
    }
  }
  __syncthreads();

  {
    const int rn64 = t >> 3;            // 0..63 : local n
    const int qg2 = rn64 >> 5, rn = rn64 & 31;
    const int c0 = (t & 7) * 16;
    float L = (lsum[qg2][rn] + lsum[qg2 + 2][rn]) + (lsum[qg2 + 4][rn] + lsum[qg2 + 6][rn]);
    if ((t & 7) == 0) linv[rn64] = 1.0f / L;
    float o[16];
#pragma unroll
    for (int i = 0; i < 16; ++i) o[i] = 0.f;
#pragma unroll
    for (int m2 = 0; m2 < 4; ++m2) {
#pragma unroll
      for (int h2 = 0; h2 < 2; ++h2) {
        bf16x8 ch = *(const bf16x8*)&accb[qg2 + 2 * m2][rn][c0 + h2 * 8];
#pragma unroll
        for (int e = 0; e < 8; ++e) o[h2 * 8 + e] += (float)ch[e];
      }
    }
    // write combined RAW (unnormalized) back into accb[qg2][rn][c0..c0+15]
#pragma unroll
    for (int h2 = 0; h2 < 2; ++h2) {
      bf16x8 sv;
#pragma unroll
      for (int e = 0; e < 8; ++e) sv[e] = (bf16_t)o[h2 * 8 + e];
      *(bf16x8*)&accb[qg2][rn][c0 + h2 * 8] = sv;
    }
  }
  __syncthreads();

  // ---- fused output projection: out = gamma*(Wo @ attn + bo) + x ----
  // out is stream-once -> NT store (no L2 allocate); x load stays cached.
  {
    const int obk = w >> 1, nh = w & 1;
    const int o0 = obk * 32;
    f32x16 oc;
#pragma unroll
    for (int i = 0; i < 16; ++i) oc[i] = 0.f;
#pragma unroll
    for (int kk = 0; kk < 8; ++kk) {
      bf16x8 wof = *(const bf16x8*)(Wob + (size_t)(o0 + l31) * 128 + kk * 16 + 8 * hi);
      bf16x8 cf = *(const bf16x8*)&accb[nh][l31][kk * 16 + 8 * hi];
      oc = MFMA32(wof, cf, oc);  // D[o][n], n = l31
    }
    const float g = gammap[0];
    const float iv = linv[nh * 32 + l31];
    const int ng = qb * 64 + nh * 32 + l31;
#pragma unroll
    for (int r = 0; r < 16; ++r) {
      int o_ = o0 + (r & 3) + 8 * (r >> 2) + 4 * hi;
      size_t off = ((size_t)(b * 128 + o_)) * 4096 + ng;
      __builtin_nontemporal_store(g * (oc[r] * iv + bo[o_]) + x[off], &out[off]);
    }
  }
}

extern "C" void kernel_launch(void* const* d_in, const int* in_sizes, int n_in,
                              void* d_out, int out_size, void* d_ws, size_t ws_size,
                              hipStream_t stream) {
  const float* x  = (const float*)d_in[0];
  const float* Wq = (const float*)d_in[1];
  const float* bq = (const float*)d_in[2];
  const float* Wk = (const float*)d_in[3];
  const float* bk = (const float*)d_in[4];
  const float* Wv = (const float*)d_in[5];
  const float* bv = (const float*)d_in[6];
  const float* Wo = (const float*)d_in[7];
  const float* bo = (const float*)d_in[8];
  const float* gm = (const float*)d_in[9];
  float* out = (float*)d_out;

  char* ws = (char*)d_ws;
  bf16_t* q   = (bf16_t*)(ws);                        // 1 MB [B][N][16]
  bf16_t* kT  = (bf16_t*)(ws + (size_t)(1 << 20));    // 1 MB [B][N][16]
  char*   vf  = (char*)  (ws + (size_t)(2 << 20));    // 4 MB fp8 K=64-tiled V (split-plane)
  bf16_t* Wob = (bf16_t*)(ws + (size_t)(6 << 20));    // 32 KB Wo bf16

  k_qkv<<<dim3(64, 8), 256, 0, stream>>>(x, Wq, bq, Wk, bk, Wv, bv, Wo, q, kT, vf, Wob);
  k_attn<<<512, 512, 0, stream>>>(q, kT, vf, Wob, bo, gm, x, out);
}